// Round 1
// baseline (636.599 us; speedup 1.0000x reference)
//
#include <hip/hip_runtime.h>
#include <hip/hip_bf16.h>

constexpr int B = 16, H = 224, W = 224, CI = 3, CO = 64, K = 7;
constexpr int SEG = 196, E = 768;
constexpr int HW = H * W;

constexpr int PATCH_H = 14;     // 8-row strip + 6 halo
constexpr int PATCH_W = 236;    // 224 + 6 halo + pad (stride %32 = 12 -> spreads banks)
constexpr int SUMP = 197;       // seg-sum LDS stride (odd -> bank spread with random r)
constexpr int PP = 201;         // pooled LDS stride

// ---------------- K2: mark present segment ids ----------------
__global__ void k_present(const int* __restrict__ seg, int* __restrict__ present) {
    int idx = blockIdx.x * 256 + threadIdx.x;
    if (idx < B * HW) {
        int b = idx / HW;
        int s = seg[idx];
        present[b * SEG + s] = 1;   // idempotent store, no atomic needed
    }
}

// ---------------- K3: per-image inclusive scan -> rank ----------------
__global__ void k_scan(const int* __restrict__ present, int* __restrict__ rank) {
    __shared__ int buf[256];
    int b = blockIdx.x, t = threadIdx.x;
    int v = (t < SEG) ? present[b * SEG + t] : 0;
    buf[t] = v;
    __syncthreads();
    for (int off = 1; off < 256; off <<= 1) {
        int u = (t >= off) ? buf[t - off] : 0;
        __syncthreads();
        buf[t] += u;
        __syncthreads();
    }
    if (t < SEG) rank[b * SEG + t] = buf[t] - 1;
}

// ---------------- K5: fused conv7x7 + pos + segment-sum ----------------
// grid (28 strips, B). 256 threads: cg=tid>>5 (8 ch-groups), ty=(tid>>2)&7, tx=tid&3.
// Each thread: 8 pixels (x) x 8 channels accumulators; 7 x-chunks of 32 cols.
__launch_bounds__(256, 1)
__global__ void k_conv_pool(const float* __restrict__ x,
                            const int* __restrict__ seg,
                            const float* __restrict__ w1,
                            const float* __restrict__ pos,
                            const int* __restrict__ rank,
                            float* __restrict__ sums,
                            unsigned* __restrict__ counts,
                            float* __restrict__ out2) {
    __shared__ float w_lds[CI * K * K * CO];      // [ci][ky][kx][co]  37632B
    __shared__ float patch[CI * PATCH_H * PATCH_W]; // 39648B
    __shared__ int   seg_r[8 * W];                 // 7168B
    __shared__ int   rank_lds[SEG];
    __shared__ float sums_lds[CO * SUMP];          // [c][r] 50432B
    __shared__ unsigned cnt_lds[SEG];

    const int tid = threadIdx.x;
    const int b  = blockIdx.y;
    const int y0 = blockIdx.x * 8;

    // ---- Phase A: zero LDS accumulators + patch, stage weights, load rank
    for (int i = tid; i < CO * SUMP; i += 256) sums_lds[i] = 0.f;
    for (int i = tid; i < SEG; i += 256) cnt_lds[i] = 0u;
    for (int i = tid; i < CI * PATCH_H * PATCH_W; i += 256) patch[i] = 0.f;
    if (tid < SEG) rank_lds[tid] = rank[b * SEG + tid];
    for (int i = tid; i < CO * CI * K * K; i += 256) {
        int co = i / (CI * K * K);
        int r  = i % (CI * K * K);
        w_lds[r * CO + co] = w1[i];
    }
    __syncthreads();

    // ---- Phase B: fill patch interior, seg ranks, f_segment out, counts
    for (int i = tid; i < CI * PATCH_H * W; i += 256) {
        int ci = i / (PATCH_H * W);
        int rr = (i / W) % PATCH_H;
        int gx = i % W;
        int gy = y0 + rr - 3;
        if (gy >= 0 && gy < H)
            patch[(ci * PATCH_H + rr) * PATCH_W + gx + 3] =
                x[((b * CI + ci) * H + gy) * W + gx];
    }
    for (int i = tid; i < 8 * W; i += 256) {
        int rr = i / W, gx = i % W;
        int gy = y0 + rr;
        int s = seg[b * HW + gy * W + gx];
        int r = rank_lds[s];
        seg_r[i] = r;
        out2[b * HW + gy * W + gx] = (float)r;
        atomicAdd(&cnt_lds[r], 1u);
    }
    __syncthreads();

    // ---- Phase C: compute
    const int cg = tid >> 5;
    const int ty = (tid >> 2) & 7;
    const int tx = tid & 3;
    const int gy = y0 + ty;

    for (int xc = 0; xc < 7; ++xc) {
        const int xb = xc * 32 + tx * 8;   // first pixel x for this thread
        float acc[8][8];
        #pragma unroll
        for (int p = 0; p < 8; ++p)
            #pragma unroll
            for (int i = 0; i < 8; ++i) acc[p][i] = 0.f;

        #pragma unroll 1
        for (int ci = 0; ci < CI; ++ci) {
            #pragma unroll 1
            for (int ky = 0; ky < K; ++ky) {
                const float* prow = &patch[(ci * PATCH_H + ty + ky) * PATCH_W + xb];
                float vals[16];
                *(float4*)&vals[0]  = *(const float4*)&prow[0];
                *(float4*)&vals[4]  = *(const float4*)&prow[4];
                *(float4*)&vals[8]  = *(const float4*)&prow[8];
                *(float4*)&vals[12] = *(const float4*)&prow[12];
                const float* wrow = &w_lds[(ci * K + ky) * K * CO + cg * 8];
                #pragma unroll
                for (int kx = 0; kx < K; ++kx) {
                    float wv[8];
                    *(float4*)&wv[0] = *(const float4*)&wrow[kx * CO];
                    *(float4*)&wv[4] = *(const float4*)&wrow[kx * CO + 4];
                    #pragma unroll
                    for (int p = 0; p < 8; ++p)
                        #pragma unroll
                        for (int i = 0; i < 8; ++i)
                            acc[p][i] = fmaf(vals[p + kx], wv[i], acc[p][i]);
                }
            }
        }
        // seg ranks for the 8 pixels
        int rr[8];
        #pragma unroll
        for (int p = 0; p < 8; ++p) rr[p] = seg_r[ty * W + xb + p];
        // add pos_embed and accumulate into LDS segment sums
        #pragma unroll
        for (int i = 0; i < 8; ++i) {
            const int c = cg * 8 + i;
            const float* pp = &pos[(c * H + gy) * W + xb];
            float4 pa = *(const float4*)&pp[0];
            float4 pb = *(const float4*)&pp[4];
            float pv[8] = {pa.x, pa.y, pa.z, pa.w, pb.x, pb.y, pb.z, pb.w};
            #pragma unroll
            for (int p = 0; p < 8; ++p)
                unsafeAtomicAdd(&sums_lds[c * SUMP + rr[p]], acc[p][i] + pv[p]);
        }
    }
    __syncthreads();

    // ---- Phase D: flush to global
    for (int i = tid; i < SEG * CO; i += 256) {
        int s = i >> 6, c = i & 63;
        unsafeAtomicAdd(&sums[(b * SEG + s) * CO + c], sums_lds[c * SUMP + s]);
    }
    for (int i = tid; i < SEG; i += 256)
        atomicAdd(&counts[b * SEG + i], cnt_lds[i]);
}

// ---------------- K6: pooled = sums/cnt + bias; conv1d k=3 -> out ----------------
// grid (12 e-chunks of 64, B). 256 threads: te=tid>>5 (8 e-subgroups of 8), txs=tid&31 (7 s each)
__launch_bounds__(256, 1)
__global__ void k_pool_conv1d(const float* __restrict__ sums,
                              const unsigned* __restrict__ counts,
                              const float* __restrict__ b1,
                              const float* __restrict__ w2,
                              const float* __restrict__ b2,
                              float* __restrict__ out0) {
    __shared__ float pooled[CO * PP];   // [c][s+1], halo zeros  51456B
    __shared__ float w2l[192 * 65];     // [c*3+dk][e]           49920B
    const int tid = threadIdx.x;
    const int b  = blockIdx.y;
    const int e0 = blockIdx.x * 64;

    for (int i = tid; i < SEG * CO; i += 256) {
        int s = i >> 6, c = i & 63;
        float cnt = (float)counts[b * SEG + s];
        float v = sums[(b * SEG + s) * CO + c];
        pooled[c * PP + s + 1] = (cnt > 0.f) ? (v / cnt + b1[c]) : 0.f;
    }
    for (int i = tid; i < CO * 5; i += 256) {
        int c = i / 5, h = i % 5;
        pooled[c * PP + (h == 0 ? 0 : 196 + h)] = 0.f;
    }
    for (int i = tid; i < 64 * 192; i += 256) {
        int e = i / 192, k = i % 192;
        w2l[k * 65 + e] = w2[(e0 + e) * 192 + k];
    }
    __syncthreads();

    const int txs = tid & 31;
    const int te  = tid >> 5;
    const int s0  = txs * 7;
    float acc[7][8];
    #pragma unroll
    for (int ss = 0; ss < 7; ++ss)
        #pragma unroll
        for (int ee = 0; ee < 8; ++ee) acc[ss][ee] = b2[e0 + te * 8 + ee];

    if (s0 < SEG) {
        #pragma unroll 2
        for (int c = 0; c < CO; ++c) {
            float pv[9];
            #pragma unroll
            for (int j = 0; j < 9; ++j) pv[j] = pooled[c * PP + s0 + j];
            #pragma unroll
            for (int dk = 0; dk < 3; ++dk) {
                float wv[8];
                #pragma unroll
                for (int ee = 0; ee < 8; ++ee) wv[ee] = w2l[(c * 3 + dk) * 65 + te * 8 + ee];
                #pragma unroll
                for (int ss = 0; ss < 7; ++ss)
                    #pragma unroll
                    for (int ee = 0; ee < 8; ++ee)
                        acc[ss][ee] = fmaf(pv[ss + dk], wv[ee], acc[ss][ee]);
            }
        }
        #pragma unroll
        for (int ss = 0; ss < 7; ++ss) {
            int s = s0 + ss;
            float* op = &out0[((b * SEG + s) * E) + e0 + te * 8];
            float4 v0 = {acc[ss][0], acc[ss][1], acc[ss][2], acc[ss][3]};
            float4 v1 = {acc[ss][4], acc[ss][5], acc[ss][6], acc[ss][7]};
            *(float4*)&op[0] = v0;
            *(float4*)&op[4] = v1;
        }
    }
}

extern "C" void kernel_launch(void* const* d_in, const int* in_sizes, int n_in,
                              void* d_out, int out_size, void* d_ws, size_t ws_size,
                              hipStream_t stream) {
    const float* x   = (const float*)d_in[0];
    const int*   seg = (const int*)d_in[1];
    const float* w1  = (const float*)d_in[2];
    const float* b1  = (const float*)d_in[3];
    const float* pos = (const float*)d_in[4];
    const float* w2  = (const float*)d_in[5];
    const float* b2  = (const float*)d_in[6];

    float* out0 = (float*)d_out;                 // [B,196,768]
    float* out2 = out0 + (size_t)B * SEG * E;    // f_segment as float [B,1,224,224]

    float*    sums    = (float*)d_ws;                       // B*SEG*CO
    unsigned* counts  = (unsigned*)(sums + B * SEG * CO);   // B*SEG
    int*      present = (int*)(counts + B * SEG);           // B*SEG
    int*      rank    = present + B * SEG;                  // B*SEG

    size_t zero_bytes = (size_t)(B * SEG * CO + 2 * B * SEG) * 4;
    hipMemsetAsync(d_ws, 0, zero_bytes, stream);

    k_present<<<dim3((B * HW + 255) / 256), 256, 0, stream>>>(seg, present);
    k_scan<<<dim3(B), 256, 0, stream>>>(present, rank);
    k_conv_pool<<<dim3(28, B), 256, 0, stream>>>(x, seg, w1, pos, rank, sums, counts, out2);
    k_pool_conv1d<<<dim3(12, B), 256, 0, stream>>>(sums, counts, b1, w2, b2, out0);
}

// Round 4
// 627.342 us; speedup vs baseline: 1.0148x; 1.0148x over previous
//
#include <hip/hip_runtime.h>
#include <hip/hip_bf16.h>

constexpr int B = 16, H = 224, W = 224, CI = 3, CO = 64, K = 7;
constexpr int SEG = 196, E = 768;
constexpr int HW = H * W;

constexpr int PATCH_H = 14;     // 8-row strip + 6 halo
constexpr int PATCH_W = 236;    // 224 + 6 halo + pad
constexpr int SUMP = 65;        // seg-sum LDS inner stride [r][c], 65 -> bank (r+c)%32
constexpr int PP = 201;         // pooled LDS stride
constexpr int EC = 32;          // conv1d e-chunk

// ---------------- K2: mark present segment ids ----------------
__global__ void k_present(const int* __restrict__ seg, int* __restrict__ present) {
    int idx = blockIdx.x * 256 + threadIdx.x;
    if (idx < B * HW) {
        int b = idx / HW;
        int s = seg[idx];
        present[b * SEG + s] = 1;   // idempotent store
    }
}

// ---------------- K3: per-image inclusive scan -> rank ----------------
__global__ void k_scan(const int* __restrict__ present, int* __restrict__ rank) {
    __shared__ int buf[256];
    int b = blockIdx.x, t = threadIdx.x;
    int v = (t < SEG) ? present[b * SEG + t] : 0;
    buf[t] = v;
    __syncthreads();
    for (int off = 1; off < 256; off <<= 1) {
        int u = (t >= off) ? buf[t - off] : 0;
        __syncthreads();
        buf[t] += u;
        __syncthreads();
    }
    if (t < SEG) rank[b * SEG + t] = buf[t] - 1;
}

// ---------------- K4: conv7x7 + bias + pos -> h (bf16) ----------------
// grid (28 strips, images_in_chunk). LDS 77.3KB -> 2 blocks/CU (8 waves/CU).
__launch_bounds__(256, 2)
__global__ void k_conv(const float* __restrict__ x,
                       const float* __restrict__ w1,
                       const float* __restrict__ b1,
                       const float* __restrict__ pos,
                       __hip_bfloat16* __restrict__ h,
                       int b0) {
    __shared__ float w_lds[CI * K * K * CO];        // [ci][ky][kx][co]  37632B
    __shared__ float patch[CI * PATCH_H * PATCH_W]; // 39648B

    const int tid = threadIdx.x;
    const int lb = blockIdx.y;          // local image index within chunk
    const int b  = b0 + lb;             // global image index
    const int y0 = blockIdx.x * 8;

    // Phase A: zero patch, stage weights
    for (int i = tid; i < CI * PATCH_H * PATCH_W; i += 256) patch[i] = 0.f;
    for (int i = tid; i < CO * CI * K * K; i += 256) {
        int co = i / (CI * K * K);
        int r  = i % (CI * K * K);
        w_lds[r * CO + co] = w1[i];
    }
    __syncthreads();

    // Phase B: fill patch interior
    for (int i = tid; i < CI * PATCH_H * W; i += 256) {
        int ci = i / (PATCH_H * W);
        int rr = (i / W) % PATCH_H;
        int gx = i % W;
        int gy = y0 + rr - 3;
        if (gy >= 0 && gy < H)
            patch[(ci * PATCH_H + rr) * PATCH_W + gx + 3] =
                x[((b * CI + ci) * H + gy) * W + gx];
    }
    __syncthreads();

    // Phase C: compute + store bf16
    const int cg = tid >> 5;
    const int ty = (tid >> 2) & 7;
    const int tx = tid & 3;
    const int gy = y0 + ty;

    float bb[8];
    #pragma unroll
    for (int i = 0; i < 8; ++i) bb[i] = b1[cg * 8 + i];

    for (int xc = 0; xc < 7; ++xc) {
        const int xb = xc * 32 + tx * 8;
        float acc[8][8];
        #pragma unroll
        for (int p = 0; p < 8; ++p)
            #pragma unroll
            for (int i = 0; i < 8; ++i) acc[p][i] = 0.f;

        #pragma unroll 1
        for (int ci = 0; ci < CI; ++ci) {
            #pragma unroll 1
            for (int ky = 0; ky < K; ++ky) {
                const float* prow = &patch[(ci * PATCH_H + ty + ky) * PATCH_W + xb];
                float vals[16];
                *(float4*)&vals[0]  = *(const float4*)&prow[0];
                *(float4*)&vals[4]  = *(const float4*)&prow[4];
                *(float4*)&vals[8]  = *(const float4*)&prow[8];
                *(float4*)&vals[12] = *(const float4*)&prow[12];
                const float* wrow = &w_lds[(ci * K + ky) * K * CO + cg * 8];
                #pragma unroll
                for (int kx = 0; kx < K; ++kx) {
                    float wv[8];
                    *(float4*)&wv[0] = *(const float4*)&wrow[kx * CO];
                    *(float4*)&wv[4] = *(const float4*)&wrow[kx * CO + 4];
                    #pragma unroll
                    for (int p = 0; p < 8; ++p)
                        #pragma unroll
                        for (int i = 0; i < 8; ++i)
                            acc[p][i] = fmaf(vals[p + kx], wv[i], acc[p][i]);
                }
            }
        }
        #pragma unroll
        for (int i = 0; i < 8; ++i) {
            const int c = cg * 8 + i;
            const float* pp = &pos[(c * H + gy) * W + xb];
            float4 pa = *(const float4*)&pp[0];
            float4 pb = *(const float4*)&pp[4];
            float pv[8] = {pa.x, pa.y, pa.z, pa.w, pb.x, pb.y, pb.z, pb.w};
            union { __hip_bfloat16 hh[8]; uint4 u; } pk;
            #pragma unroll
            for (int p = 0; p < 8; ++p)
                pk.hh[p] = __float2bfloat16(acc[p][i] + pv[p] + bb[i]);
            *(uint4*)&h[(size_t)(lb * CO + c) * HW + gy * W + xb] = pk.u;
        }
    }
}

// ---------------- K5: segment pooling from h ----------------
// grid (28 strips, images_in_chunk). LDS ~60KB -> 2 blocks/CU. Memory-bound.
__launch_bounds__(256, 2)
__global__ void k_pool(const __hip_bfloat16* __restrict__ h,
                       const int* __restrict__ seg,
                       const int* __restrict__ rank,
                       float* __restrict__ sums,
                       unsigned* __restrict__ counts,
                       float* __restrict__ out2,
                       int b0) {
    __shared__ float sums_lds[SEG * SUMP];  // [r][c] stride 65 -> 50960B
    __shared__ unsigned cnt_lds[SEG];
    __shared__ int rank_lds[SEG];
    __shared__ int seg_r[8 * W];            // 7168B

    const int tid = threadIdx.x;
    const int lb = blockIdx.y;
    const int b  = b0 + lb;
    const int y0 = blockIdx.x * 8;

    for (int i = tid; i < SEG * SUMP; i += 256) sums_lds[i] = 0.f;
    for (int i = tid; i < SEG; i += 256) cnt_lds[i] = 0u;
    if (tid < SEG) rank_lds[tid] = rank[b * SEG + tid];
    __syncthreads();

    // Phase B: ranks, f_segment out, counts
    for (int i = tid; i < 8 * W; i += 256) {
        int s = seg[b * HW + y0 * W + i];
        int r = rank_lds[s];
        seg_r[i] = r;
        out2[b * HW + y0 * W + i] = (float)r;
        atomicAdd(&cnt_lds[r], 1u);
    }
    __syncthreads();

    // Phase C: accumulate h into segment sums. i -> (c, octet)
    for (int i = tid; i < CO * 224; i += 256) {
        int c = i / 224;
        int o = i % 224;     // octet within strip (1792 px = 224 octets, contiguous)
        uint4 u = *(const uint4*)&h[(size_t)(lb * CO + c) * HW + y0 * W + o * 8];
        const unsigned* uw = &u.x;
        #pragma unroll
        for (int j = 0; j < 4; ++j) {
            float flo = __uint_as_float((uw[j] & 0xffffu) << 16);
            float fhi = __uint_as_float(uw[j] & 0xffff0000u);
            int r0 = seg_r[o * 8 + j * 2];
            int r1 = seg_r[o * 8 + j * 2 + 1];
            unsafeAtomicAdd(&sums_lds[r0 * SUMP + c], flo);
            unsafeAtomicAdd(&sums_lds[r1 * SUMP + c], fhi);
        }
    }
    __syncthreads();

    // Phase D: flush
    for (int i = tid; i < SEG * CO; i += 256) {
        int s = i >> 6, c = i & 63;
        unsafeAtomicAdd(&sums[(b * SEG + s) * CO + c], sums_lds[s * SUMP + c]);
    }
    for (int i = tid; i < SEG; i += 256)
        atomicAdd(&counts[b * SEG + i], cnt_lds[i]);
}

// ---------------- K6: pooled = sums/cnt + bias; conv1d k=3 -> out ----------------
// grid (24 e-chunks of 32, B). LDS 76.8KB -> 2 blocks/CU.
__launch_bounds__(256, 2)
__global__ void k_pool_conv1d(const float* __restrict__ sums,
                              const unsigned* __restrict__ counts,
                              const float* __restrict__ b1,
                              const float* __restrict__ w2,
                              const float* __restrict__ b2,
                              float* __restrict__ out0) {
    __shared__ float pooled[CO * PP];        // [c][s+1], halo zeros  51456B
    __shared__ float w2l[192 * (EC + 1)];    // [c*3+dk][e]           25344B
    const int tid = threadIdx.x;
    const int b  = blockIdx.y;
    const int e0 = blockIdx.x * EC;

    for (int i = tid; i < SEG * CO; i += 256) {
        int s = i >> 6, c = i & 63;
        float cnt = (float)counts[b * SEG + s];
        float v = sums[(b * SEG + s) * CO + c];
        pooled[c * PP + s + 1] = (cnt > 0.f) ? (v / cnt + b1[c]) : 0.f;
    }
    for (int i = tid; i < CO * 5; i += 256) {
        int c = i / 5, hh = i % 5;
        pooled[c * PP + (hh == 0 ? 0 : 196 + hh)] = 0.f;
    }
    for (int i = tid; i < EC * 192; i += 256) {
        int e = i / 192, k = i % 192;
        w2l[k * (EC + 1) + e] = w2[(size_t)(e0 + e) * 192 + k];
    }
    __syncthreads();

    const int txs = tid & 31;
    const int te  = tid >> 5;       // 8 groups of 4 e's
    const int s0  = txs * 7;
    float acc[7][4];
    #pragma unroll
    for (int ss = 0; ss < 7; ++ss)
        #pragma unroll
        for (int ee = 0; ee < 4; ++ee) acc[ss][ee] = b2[e0 + te * 4 + ee];

    if (s0 < SEG) {
        #pragma unroll 4
        for (int c = 0; c < CO; ++c) {
            float pv[9];
            #pragma unroll
            for (int j = 0; j < 9; ++j) pv[j] = pooled[c * PP + s0 + j];
            #pragma unroll
            for (int dk = 0; dk < 3; ++dk) {
                float wv[4];
                #pragma unroll
                for (int ee = 0; ee < 4; ++ee)
                    wv[ee] = w2l[(c * 3 + dk) * (EC + 1) + te * 4 + ee];
                #pragma unroll
                for (int ss = 0; ss < 7; ++ss)
                    #pragma unroll
                    for (int ee = 0; ee < 4; ++ee)
                        acc[ss][ee] = fmaf(pv[ss + dk], wv[ee], acc[ss][ee]);
            }
        }
        #pragma unroll
        for (int ss = 0; ss < 7; ++ss) {
            int s = s0 + ss;
            float* op = &out0[((size_t)(b * SEG + s) * E) + e0 + te * 4];
            float4 v0 = {acc[ss][0], acc[ss][1], acc[ss][2], acc[ss][3]};
            *(float4*)op = v0;
        }
    }
}

extern "C" void kernel_launch(void* const* d_in, const int* in_sizes, int n_in,
                              void* d_out, int out_size, void* d_ws, size_t ws_size,
                              hipStream_t stream) {
    const float* x   = (const float*)d_in[0];
    const int*   seg = (const int*)d_in[1];
    const float* w1  = (const float*)d_in[2];
    const float* b1  = (const float*)d_in[3];
    const float* pos = (const float*)d_in[4];
    const float* w2  = (const float*)d_in[5];
    const float* b2  = (const float*)d_in[6];

    float* out0 = (float*)d_out;                 // [B,196,768]
    float* out2 = out0 + (size_t)B * SEG * E;    // f_segment as float [B,1,224,224]

    float*    sums    = (float*)d_ws;                       // B*SEG*CO
    unsigned* counts  = (unsigned*)(sums + B * SEG * CO);   // B*SEG
    int*      present = (int*)(counts + B * SEG);           // B*SEG
    int*      rank    = present + B * SEG;                  // B*SEG
    __hip_bfloat16* hbuf = (__hip_bfloat16*)((char*)d_ws + (1 << 20)); // h chunk

    // zero sums + counts + present
    size_t zero_bytes = (size_t)(B * SEG * CO + 2 * B * SEG) * 4;
    hipMemsetAsync(d_ws, 0, zero_bytes, stream);

    k_present<<<dim3((B * HW + 255) / 256), 256, 0, stream>>>(seg, present);
    k_scan<<<dim3(B), 256, 0, stream>>>(present, rank);

    // how many images' h fit in remaining workspace
    size_t h_per_img = (size_t)CO * HW * sizeof(__hip_bfloat16);  // 6.42 MB
    size_t avail = (ws_size > (1 << 20)) ? ws_size - (1 << 20) : 0;
    int ipc = (int)(avail / h_per_img);
    if (ipc < 1) ipc = 1;
    if (ipc > B) ipc = B;

    for (int b0 = 0; b0 < B; b0 += ipc) {
        int nb = (b0 + ipc <= B) ? ipc : (B - b0);
        k_conv<<<dim3(28, nb), 256, 0, stream>>>(x, w1, b1, pos, hbuf, b0);
        k_pool<<<dim3(28, nb), 256, 0, stream>>>(hbuf, seg, rank, sums, counts, out2, b0);
    }
    k_pool_conv1d<<<dim3(24, B), 256, 0, stream>>>(sums, counts, b1, w2, b2, out0);
}

// Round 5
// 330.072 us; speedup vs baseline: 1.9287x; 1.9006x over previous
//
#include <hip/hip_runtime.h>
#include <hip/hip_bf16.h>

constexpr int B = 16, H = 224, W = 224, CI = 3, CO = 64, K = 7;
constexpr int SEG = 196, E = 768;
constexpr int HW = H * W;

constexpr int PATCH_H = 14;     // 8-row strip + 6 halo
constexpr int PATCH_W = 236;    // 224 + 6 halo + pad
constexpr int PP = 201;         // pooled LDS stride
constexpr int EC = 32;          // conv1d e-chunk

// ---------------- kA: present flags + raw-id histogram ----------------
__global__ void k_count(const int* __restrict__ seg, int* __restrict__ present,
                        unsigned* __restrict__ counts_raw) {
    __shared__ unsigned cnt[SEG];
    const int tid = threadIdx.x, b = blockIdx.y, y0 = blockIdx.x * 8;
    for (int i = tid; i < SEG; i += 256) cnt[i] = 0u;
    __syncthreads();
    for (int i = tid; i < 8 * W; i += 256) {
        int s = seg[b * HW + y0 * W + i];
        present[b * SEG + s] = 1;                 // idempotent
        atomicAdd(&cnt[s], 1u);
    }
    __syncthreads();
    for (int i = tid; i < SEG; i += 256)
        if (cnt[i]) atomicAdd(&counts_raw[b * SEG + i], cnt[i]);
}

// ---------------- kB: per-image scans -> rank, offsets, cursors ----------------
__global__ void k_offsets(const int* __restrict__ present,
                          const unsigned* __restrict__ counts_raw,
                          int* __restrict__ rank, int* __restrict__ off_rank,
                          int* __restrict__ cnt_rank, unsigned* __restrict__ cursor) {
    __shared__ int buf[256];
    const int b = blockIdx.x, t = threadIdx.x;
    int pres = (t < SEG) ? present[b * SEG + t] : 0;
    int cv   = (t < SEG) ? (int)counts_raw[b * SEG + t] : 0;
    // scan 1 (inclusive) over present -> rank
    buf[t] = pres; __syncthreads();
    for (int off = 1; off < 256; off <<= 1) {
        int u = (t >= off) ? buf[t - off] : 0; __syncthreads();
        buf[t] += u; __syncthreads();
    }
    int rk = buf[t] - 1;
    if (t < SEG) rank[b * SEG + t] = rk;
    __syncthreads();
    // scan 2 (inclusive) over counts -> exclusive offsets
    buf[t] = cv; __syncthreads();
    for (int off = 1; off < 256; off <<= 1) {
        int u = (t >= off) ? buf[t - off] : 0; __syncthreads();
        buf[t] += u; __syncthreads();
    }
    int offx = buf[t] - cv;
    if (t < SEG) {
        cursor[b * SEG + t] = (unsigned)offx;
        cnt_rank[b * SEG + t] = 0;
        off_rank[b * SEG + t] = 0;
    }
    __syncthreads();
    if (t < SEG && pres) {
        cnt_rank[b * SEG + rk] = cv;
        off_rank[b * SEG + rk] = offx;
    }
}

// ---------------- kC: bucket pixel indices per segment + f_segment out ----------------
__global__ void k_scatter(const int* __restrict__ seg, const int* __restrict__ rank,
                          unsigned* __restrict__ cursor, unsigned* __restrict__ bucket,
                          float* __restrict__ out2) {
    __shared__ unsigned bcnt[SEG];
    __shared__ int base_l[SEG];
    __shared__ int rank_lds[SEG];
    __shared__ unsigned char ss[8 * W];
    __shared__ unsigned short lp[8 * W];
    const int tid = threadIdx.x, b = blockIdx.y, y0 = blockIdx.x * 8;
    for (int i = tid; i < SEG; i += 256) { bcnt[i] = 0u; rank_lds[i] = rank[b * SEG + i]; }
    __syncthreads();
    for (int i = tid; i < 8 * W; i += 256) {
        int s = seg[b * HW + y0 * W + i];
        ss[i] = (unsigned char)s;
        out2[b * HW + y0 * W + i] = (float)rank_lds[s];
        lp[i] = (unsigned short)atomicAdd(&bcnt[s], 1u);
    }
    __syncthreads();
    for (int i = tid; i < SEG; i += 256)
        if (bcnt[i]) base_l[i] = (int)atomicAdd(&cursor[b * SEG + i], bcnt[i]);
    __syncthreads();
    for (int i = tid; i < 8 * W; i += 256) {
        int s = ss[i];
        bucket[b * HW + base_l[s] + lp[i]] = (unsigned)(y0 * W + i);
    }
}

// ---------------- k_conv: conv7x7 + bias + pos -> h_t pixel-major bf16 ----------------
// grid (images_in_chunk, 28 strips): consecutive blocks share a strip's pos slice (L2).
__launch_bounds__(256, 2)
__global__ void k_conv(const float* __restrict__ x,
                       const float* __restrict__ w1,
                       const float* __restrict__ b1,
                       const float* __restrict__ pos,
                       __hip_bfloat16* __restrict__ h,
                       int b0) {
    __shared__ float w_lds[CI * K * K * CO];        // [ci][ky][kx][co]  37632B
    __shared__ float patch[CI * PATCH_H * PATCH_W]; // 39648B

    const int tid = threadIdx.x;
    const int lb = blockIdx.x;          // local image index within chunk
    const int b  = b0 + lb;             // global image index
    const int y0 = blockIdx.y * 8;

    for (int i = tid; i < CI * PATCH_H * PATCH_W; i += 256) patch[i] = 0.f;
    for (int i = tid; i < CO * CI * K * K; i += 256) {
        int co = i / (CI * K * K);
        int r  = i % (CI * K * K);
        w_lds[r * CO + co] = w1[i];
    }
    __syncthreads();

    for (int i = tid; i < CI * PATCH_H * W; i += 256) {
        int ci = i / (PATCH_H * W);
        int rr = (i / W) % PATCH_H;
        int gx = i % W;
        int gy = y0 + rr - 3;
        if (gy >= 0 && gy < H)
            patch[(ci * PATCH_H + rr) * PATCH_W + gx + 3] =
                x[((b * CI + ci) * H + gy) * W + gx];
    }
    __syncthreads();

    const int cg = tid >> 5;
    const int ty = (tid >> 2) & 7;
    const int tx = tid & 3;
    const int gy = y0 + ty;

    float bb[8];
    #pragma unroll
    for (int i = 0; i < 8; ++i) bb[i] = b1[cg * 8 + i];

    for (int xc = 0; xc < 7; ++xc) {
        const int xb = xc * 32 + tx * 8;
        float acc[8][8];
        #pragma unroll
        for (int p = 0; p < 8; ++p)
            #pragma unroll
            for (int i = 0; i < 8; ++i) acc[p][i] = 0.f;

        #pragma unroll 1
        for (int ci = 0; ci < CI; ++ci) {
            #pragma unroll 1
            for (int ky = 0; ky < K; ++ky) {
                const float* prow = &patch[(ci * PATCH_H + ty + ky) * PATCH_W + xb];
                float vals[16];
                *(float4*)&vals[0]  = *(const float4*)&prow[0];
                *(float4*)&vals[4]  = *(const float4*)&prow[4];
                *(float4*)&vals[8]  = *(const float4*)&prow[8];
                *(float4*)&vals[12] = *(const float4*)&prow[12];
                const float* wrow = &w_lds[(ci * K + ky) * K * CO + cg * 8];
                #pragma unroll
                for (int kx = 0; kx < K; ++kx) {
                    float wv[8];
                    *(float4*)&wv[0] = *(const float4*)&wrow[kx * CO];
                    *(float4*)&wv[4] = *(const float4*)&wrow[kx * CO + 4];
                    #pragma unroll
                    for (int p = 0; p < 8; ++p)
                        #pragma unroll
                        for (int i = 0; i < 8; ++i)
                            acc[p][i] = fmaf(vals[p + kx], wv[i], acc[p][i]);
                }
            }
        }
        // add pos + bias per channel
        #pragma unroll
        for (int i = 0; i < 8; ++i) {
            const int c = cg * 8 + i;
            const float* pp = &pos[(c * H + gy) * W + xb];
            float4 pa = *(const float4*)&pp[0];
            float4 pb = *(const float4*)&pp[4];
            float pv[8] = {pa.x, pa.y, pa.z, pa.w, pb.x, pb.y, pb.z, pb.w};
            #pragma unroll
            for (int p = 0; p < 8; ++p) acc[p][i] += pv[p] + bb[i];
        }
        // store pixel-major: pixel stride = 64 ch * 2B = 128B
        #pragma unroll
        for (int p = 0; p < 8; ++p) {
            union { __hip_bfloat16 hh[8]; uint4 u; } pk;
            #pragma unroll
            for (int i = 0; i < 8; ++i) pk.hh[i] = __float2bfloat16(acc[p][i]);
            *(uint4*)&h[((size_t)lb * HW + gy * W + xb + p) * CO + cg * 8] = pk.u;
        }
    }
}

// ---------------- kD: gather-reduce per (image, rank) -> pooled mean ----------------
// grid (49 rank-quads, images_in_chunk), 256 thr = 4 waves, wave owns one rank.
// lane = px_slot(>>3) x ch_group(&7): 8 lanes read one pixel's 128B vector coalesced.
__global__ void k_gather(const __hip_bfloat16* __restrict__ h,
                         const unsigned* __restrict__ bucket,
                         const int* __restrict__ off_rank,
                         const int* __restrict__ cnt_rank,
                         float* __restrict__ pooled, int b0) {
    const int tid = threadIdx.x;
    const int wave = tid >> 6, lane = tid & 63;
    const int r = blockIdx.x * 4 + wave;
    const int lb = blockIdx.y, b = b0 + lb;
    const int n = cnt_rank[b * SEG + r];
    const int base = off_rank[b * SEG + r];
    const int ps = lane >> 3, cg = lane & 7;

    float acc[8] = {0.f, 0.f, 0.f, 0.f, 0.f, 0.f, 0.f, 0.f};
    const unsigned* bk = &bucket[b * HW + base];
    const int iters = (n + 7) >> 3;
    for (int i = 0; i < iters; ++i) {
        int idx = i * 8 + ps;
        if (idx < n) {
            unsigned p = bk[idx];
            uint4 u = *(const uint4*)&h[((size_t)lb * HW + p) * CO + cg * 8];
            acc[0] += __uint_as_float((u.x & 0xffffu) << 16);
            acc[1] += __uint_as_float(u.x & 0xffff0000u);
            acc[2] += __uint_as_float((u.y & 0xffffu) << 16);
            acc[3] += __uint_as_float(u.y & 0xffff0000u);
            acc[4] += __uint_as_float((u.z & 0xffffu) << 16);
            acc[5] += __uint_as_float(u.z & 0xffff0000u);
            acc[6] += __uint_as_float((u.w & 0xffffu) << 16);
            acc[7] += __uint_as_float(u.w & 0xffff0000u);
        }
    }
    // reduce across the 8 px_slots (lane bits 3..5)
    #pragma unroll
    for (int m = 8; m < 64; m <<= 1)
        #pragma unroll
        for (int j = 0; j < 8; ++j) acc[j] += __shfl_xor(acc[j], m, 64);

    if (ps == 0) {
        float inv = (n > 0) ? 1.f / (float)n : 0.f;
        float* op = &pooled[((size_t)b * SEG + r) * CO + cg * 8];
        float4 v0 = {acc[0] * inv, acc[1] * inv, acc[2] * inv, acc[3] * inv};
        float4 v1 = {acc[4] * inv, acc[5] * inv, acc[6] * inv, acc[7] * inv};
        *(float4*)&op[0] = v0;
        *(float4*)&op[4] = v1;
    }
}

// ---------------- kE: conv1d k=3 over pooled -> out ----------------
__launch_bounds__(256, 2)
__global__ void k_pool_conv1d(const float* __restrict__ pooledg,
                              const float* __restrict__ w2,
                              const float* __restrict__ b2,
                              float* __restrict__ out0) {
    __shared__ float pooled[CO * PP];        // [c][s+1], halo zeros  51456B
    __shared__ float w2l[192 * (EC + 1)];    // [c*3+dk][e]           25344B
    const int tid = threadIdx.x;
    const int b  = blockIdx.y;
    const int e0 = blockIdx.x * EC;

    for (int i = tid; i < SEG * CO; i += 256) {
        int s = i >> 6, c = i & 63;
        pooled[c * PP + s + 1] = pooledg[((size_t)b * SEG + s) * CO + c];
    }
    for (int i = tid; i < CO * 5; i += 256) {
        int c = i / 5, hh = i % 5;
        pooled[c * PP + (hh == 0 ? 0 : 196 + hh)] = 0.f;
    }
    for (int i = tid; i < EC * 192; i += 256) {
        int e = i / 192, k = i % 192;
        w2l[k * (EC + 1) + e] = w2[(size_t)(e0 + e) * 192 + k];
    }
    __syncthreads();

    const int txs = tid & 31;
    const int te  = tid >> 5;
    const int s0  = txs * 7;
    float acc[7][4];
    #pragma unroll
    for (int ss = 0; ss < 7; ++ss)
        #pragma unroll
        for (int ee = 0; ee < 4; ++ee) acc[ss][ee] = b2[e0 + te * 4 + ee];

    if (s0 < SEG) {
        #pragma unroll 4
        for (int c = 0; c < CO; ++c) {
            float pv[9];
            #pragma unroll
            for (int j = 0; j < 9; ++j) pv[j] = pooled[c * PP + s0 + j];
            #pragma unroll
            for (int dk = 0; dk < 3; ++dk) {
                float wv[4];
                #pragma unroll
                for (int ee = 0; ee < 4; ++ee)
                    wv[ee] = w2l[(c * 3 + dk) * (EC + 1) + te * 4 + ee];
                #pragma unroll
                for (int ss = 0; ss < 7; ++ss)
                    #pragma unroll
                    for (int ee = 0; ee < 4; ++ee)
                        acc[ss][ee] = fmaf(pv[ss + dk], wv[ee], acc[ss][ee]);
            }
        }
        #pragma unroll
        for (int ss = 0; ss < 7; ++ss) {
            int s = s0 + ss;
            float* op = &out0[((size_t)(b * SEG + s) * E) + e0 + te * 4];
            float4 v0 = {acc[ss][0], acc[ss][1], acc[ss][2], acc[ss][3]};
            *(float4*)op = v0;
        }
    }
}

extern "C" void kernel_launch(void* const* d_in, const int* in_sizes, int n_in,
                              void* d_out, int out_size, void* d_ws, size_t ws_size,
                              hipStream_t stream) {
    const float* x   = (const float*)d_in[0];
    const int*   seg = (const int*)d_in[1];
    const float* w1  = (const float*)d_in[2];
    const float* b1  = (const float*)d_in[3];
    const float* pos = (const float*)d_in[4];
    const float* w2  = (const float*)d_in[5];
    const float* b2  = (const float*)d_in[6];

    float* out0 = (float*)d_out;                 // [B,196,768]
    float* out2 = out0 + (size_t)B * SEG * E;    // f_segment as float [B,1,224,224]

    // workspace layout (present+counts_raw first: they are the memset range)
    int*      present    = (int*)d_ws;                        // B*SEG  [zeroed]
    unsigned* counts_raw = (unsigned*)(present + B * SEG);    // B*SEG  [zeroed]
    int*      rank       = (int*)(counts_raw + B * SEG);      // B*SEG
    int*      off_rank   = rank + B * SEG;                    // B*SEG
    int*      cnt_rank   = off_rank + B * SEG;                // B*SEG
    unsigned* cursor     = (unsigned*)(cnt_rank + B * SEG);   // B*SEG
    float*    pooled     = (float*)(cursor + B * SEG);        // B*SEG*CO
    unsigned* bucket     = (unsigned*)(pooled + (size_t)B * SEG * CO); // B*HW
    __hip_bfloat16* hbuf = (__hip_bfloat16*)(bucket + (size_t)B * HW);

    hipMemsetAsync(d_ws, 0, (size_t)2 * B * SEG * 4, stream);

    k_count  <<<dim3(28, B), 256, 0, stream>>>(seg, present, counts_raw);
    k_offsets<<<dim3(B),     256, 0, stream>>>(present, counts_raw, rank, off_rank, cnt_rank, cursor);
    k_scatter<<<dim3(28, B), 256, 0, stream>>>(seg, rank, cursor, bucket, out2);

    size_t used = (char*)hbuf - (char*)d_ws;
    size_t h_per_img = (size_t)HW * CO * sizeof(__hip_bfloat16);  // 6.42 MB
    size_t avail = (ws_size > used) ? ws_size - used : 0;
    int ipc = (int)(avail / h_per_img);
    if (ipc < 1) ipc = 1;
    if (ipc > B) ipc = B;

    for (int b0 = 0; b0 < B; b0 += ipc) {
        int nb = (b0 + ipc <= B) ? ipc : (B - b0);
        k_conv  <<<dim3(nb, 28), 256, 0, stream>>>(x, w1, b1, pos, hbuf, b0);
        k_gather<<<dim3(49, nb), 256, 0, stream>>>(hbuf, bucket, off_rank, cnt_rank, pooled, b0);
    }
    k_pool_conv1d<<<dim3(24, B), 256, 0, stream>>>(pooled, w2, b2, out0);
}

// Round 6
// 248.484 us; speedup vs baseline: 2.5619x; 1.3283x over previous
//
#include <hip/hip_runtime.h>
#include <hip/hip_bf16.h>

constexpr int B = 16, H = 224, W = 224, CI = 3, CO = 64, K = 7;
constexpr int SEG = 196, E = 768;
constexpr int HW = H * W;
constexpr int PP = 201;         // pooled LDS stride
constexpr int EC = 32;          // conv1d e-chunk

constexpr int TSLOTS = 10;      // T ring rows (4 concurrent y + 6 halo)
constexpr int TROW = 72;        // bf16 per T x-entry (32 used + pad) = 144B, 16B-aligned
constexpr int TX = 32;          // x entries per chunk (one 32-px M-tile)

typedef __attribute__((ext_vector_type(8))) short bf16x8;
typedef __attribute__((ext_vector_type(16))) float f32x16;

__device__ inline unsigned short bfb(float f) {
    union { __hip_bfloat16 h; unsigned short u; } cv; cv.h = __float2bfloat16(f); return cv.u;
}
__device__ inline unsigned pack2(float lo, float hi) {
    return (unsigned)bfb(lo) | ((unsigned)bfb(hi) << 16);
}
__device__ inline float bf2f(unsigned short u) {
    return __uint_as_float(((unsigned)u) << 16);
}

// ---------------- kA: present flags + raw-id histogram ----------------
__global__ void k_count(const int* __restrict__ seg, int* __restrict__ present,
                        unsigned* __restrict__ counts_raw) {
    __shared__ unsigned cnt[SEG];
    const int tid = threadIdx.x, b = blockIdx.y, y0 = blockIdx.x * 8;
    for (int i = tid; i < SEG; i += 256) cnt[i] = 0u;
    __syncthreads();
    for (int i = tid; i < 8 * W; i += 256) {
        int s = seg[b * HW + y0 * W + i];
        present[b * SEG + s] = 1;
        atomicAdd(&cnt[s], 1u);
    }
    __syncthreads();
    for (int i = tid; i < SEG; i += 256)
        if (cnt[i]) atomicAdd(&counts_raw[b * SEG + i], cnt[i]);
}

// ---------------- kB: per-image scans -> rank, offsets, cursors ----------------
__global__ void k_offsets(const int* __restrict__ present,
                          const unsigned* __restrict__ counts_raw,
                          int* __restrict__ rank, int* __restrict__ off_rank,
                          int* __restrict__ cnt_rank, unsigned* __restrict__ cursor) {
    __shared__ int buf[256];
    const int b = blockIdx.x, t = threadIdx.x;
    int pres = (t < SEG) ? present[b * SEG + t] : 0;
    int cv   = (t < SEG) ? (int)counts_raw[b * SEG + t] : 0;
    buf[t] = pres; __syncthreads();
    for (int off = 1; off < 256; off <<= 1) {
        int u = (t >= off) ? buf[t - off] : 0; __syncthreads();
        buf[t] += u; __syncthreads();
    }
    int rk = buf[t] - 1;
    if (t < SEG) rank[b * SEG + t] = rk;
    __syncthreads();
    buf[t] = cv; __syncthreads();
    for (int off = 1; off < 256; off <<= 1) {
        int u = (t >= off) ? buf[t - off] : 0; __syncthreads();
        buf[t] += u; __syncthreads();
    }
    int offx = buf[t] - cv;
    if (t < SEG) {
        cursor[b * SEG + t] = (unsigned)offx;
        cnt_rank[b * SEG + t] = 0;
        off_rank[b * SEG + t] = 0;
    }
    __syncthreads();
    if (t < SEG && pres) {
        cnt_rank[b * SEG + rk] = cv;
        off_rank[b * SEG + rk] = offx;
    }
}

// ---------------- kC: bucket pixel indices per segment + f_segment out ----------------
__global__ void k_scatter(const int* __restrict__ seg, const int* __restrict__ rank,
                          unsigned* __restrict__ cursor, unsigned* __restrict__ bucket,
                          float* __restrict__ out2) {
    __shared__ unsigned bcnt[SEG];
    __shared__ int base_l[SEG];
    __shared__ int rank_lds[SEG];
    __shared__ unsigned char ss[8 * W];
    __shared__ unsigned short lp[8 * W];
    const int tid = threadIdx.x, b = blockIdx.y, y0 = blockIdx.x * 8;
    for (int i = tid; i < SEG; i += 256) { bcnt[i] = 0u; rank_lds[i] = rank[b * SEG + i]; }
    __syncthreads();
    for (int i = tid; i < 8 * W; i += 256) {
        int s = seg[b * HW + y0 * W + i];
        ss[i] = (unsigned char)s;
        out2[b * HW + y0 * W + i] = (float)rank_lds[s];
        lp[i] = (unsigned short)atomicAdd(&bcnt[s], 1u);
    }
    __syncthreads();
    for (int i = tid; i < SEG; i += 256)
        if (bcnt[i]) base_l[i] = (int)atomicAdd(&cursor[b * SEG + i], bcnt[i]);
    __syncthreads();
    for (int i = tid; i < 8 * W; i += 256) {
        int s = ss[i];
        bucket[b * HW + base_l[s] + lp[i]] = (unsigned)(y0 * W + i);
    }
}

// ---------------- k_post: transpose pos [64][HW] f32 -> pos_t [HW][64] bf16 ----------------
__global__ void k_post(const float* __restrict__ pos, unsigned short* __restrict__ pos_t) {
    const int p = blockIdx.x * 256 + threadIdx.x;
    unsigned d[32];
    #pragma unroll
    for (int c = 0; c < 32; ++c) {
        float v0 = pos[(size_t)(2 * c) * HW + p];
        float v1 = pos[(size_t)(2 * c + 1) * HW + p];
        d[c] = pack2(v0, v1);
    }
    uint4* op = (uint4*)&pos_t[(size_t)p * 64];
    #pragma unroll
    for (int q = 0; q < 8; ++q) {
        uint4 v = {d[4 * q], d[4 * q + 1], d[4 * q + 2], d[4 * q + 3]};
        op[q] = v;
    }
}

// ---------------- k_conv_mfma: conv7x7 via bf16 MFMA + bias + pos -> h pixel-major bf16 ----
// grid (img, 7 x-chunks of 32, 8 y-strips of 28). 256 thr = 4 waves, wave w owns row ys+w.
// K-order: kk = ci*8+kx (kx=7 slot & kk>=24 zeroed). A-frag = 1 ds_read_b128 from T.
__launch_bounds__(256, 2)
__global__ void k_conv_mfma(const float* __restrict__ x,
                            const float* __restrict__ w1,
                            const float* __restrict__ b1,
                            const unsigned short* __restrict__ pos_t,
                            __hip_bfloat16* __restrict__ h, int b0) {
    __shared__ unsigned short Tl[TSLOTS * TX * TROW];   // 46080 B
    __shared__ unsigned short Wl[7 * 32 * 64];          // 28672 B

    const int tid = threadIdx.x;
    const int lb  = blockIdx.x;
    const int b   = b0 + lb;
    const int x0  = blockIdx.y * 32;
    const int y0  = blockIdx.z * 28;
    const int lane = tid & 63;
    const int ln31 = lane & 31;
    const int g    = lane >> 5;

    // zero T ring (pad slots must stay 0) + W
    for (int i = tid; i < TSLOTS * TX * TROW; i += 256) Tl[i] = 0;
    for (int i = tid; i < 7 * 32 * 64; i += 256) Wl[i] = 0;
    __syncthreads();

    // stage W: w1[co][ci][ky][kx] -> Wl[ky][ci*8+kx][co] bf16
    for (int i = tid; i < CO * CI * K * K; i += 256) {
        int co = i / 147, rem = i % 147;
        int ci = rem / 49, kyx = rem % 49;
        int ky = kyx / 7, kx = kyx % 7;
        Wl[(ky * 32 + ci * 8 + kx) * 64 + co] = bfb(w1[i]);
    }

    // T-row builder: row r -> slot (r+3)%10; entry (x_local, ci) = 8 bf16 window
    auto build = [&](int rbase, int nrows) {
        for (int idx = tid; idx < 96 * nrows; idx += 256) {
            int j = idx / 96, rem = idx % 96;
            int ci = rem >> 5, xl = rem & 31;
            int r = rbase + j;
            unsigned slot = (unsigned)(r + 3) % TSLOTS;
            unsigned d0 = 0, d1 = 0, d2 = 0, d3 = 0;
            if (r >= 0 && r < H) {
                const float* xr = &x[((size_t)(b * CI + ci) * H + r) * W];
                float v[7];
                #pragma unroll
                for (int kx = 0; kx < 7; ++kx) {
                    int gx = x0 + xl - 3 + kx;
                    v[kx] = (gx >= 0 && gx < W) ? xr[gx] : 0.f;
                }
                d0 = pack2(v[0], v[1]); d1 = pack2(v[2], v[3]);
                d2 = pack2(v[4], v[5]); d3 = pack2(v[6], 0.f);
            }
            uint4 dv = {d0, d1, d2, d3};
            *(uint4*)&Tl[(slot * TX + xl) * TROW + ci * 8] = dv;
        }
    };

    build(y0 - 3, TSLOTS);   // rows y0-3 .. y0+6
    __syncthreads();

    // hoist B-fragments: Wl[ky][kstep*16 + (l>>5)*8 + e][cog*32 + ln31]
    bf16x8 bfr[7][2][2];
    #pragma unroll
    for (int ky = 0; ky < 7; ++ky)
        #pragma unroll
        for (int ks = 0; ks < 2; ++ks)
            #pragma unroll
            for (int cg = 0; cg < 2; ++cg) {
                bf16x8 f;
                #pragma unroll
                for (int e = 0; e < 8; ++e)
                    f[e] = (short)Wl[(ky * 32 + ks * 16 + g * 8 + e) * 64 + cg * 32 + ln31];
                bfr[ky][ks][cg] = f;
            }
    const float b1v0 = b1[ln31];
    const float b1v1 = b1[32 + ln31];

    for (int s = 0; s < 7; ++s) {
        const int ys = y0 + s * 4;
        const int y  = ys + (tid >> 6);

        f32x16 c0 = {0.f}; f32x16 c1 = {0.f};
        #pragma unroll
        for (int i = 0; i < 16; ++i) { c0[i] = 0.f; c1[i] = 0.f; }

        #pragma unroll
        for (int ky = 0; ky < 7; ++ky) {
            unsigned slot = (unsigned)(y + ky) % TSLOTS;   // row y+ky-3
            const unsigned short* trow = &Tl[slot * TX * TROW];
            #pragma unroll
            for (int ks = 0; ks < 2; ++ks) {
                bf16x8 a = *(const bf16x8*)&trow[ln31 * TROW + ks * 16 + g * 8];
                c0 = __builtin_amdgcn_mfma_f32_32x32x16_bf16(a, bfr[ky][ks][0], c0, 0, 0, 0);
                c1 = __builtin_amdgcn_mfma_f32_32x32x16_bf16(a, bfr[ky][ks][1], c1, 0, 0, 0);
            }
        }

        // epilogue: C col(co)=ln31, row(px)=(reg&3)+8*(reg>>2)+4*g
        #pragma unroll
        for (int reg = 0; reg < 16; ++reg) {
            int pxl = (reg & 3) + 8 * (reg >> 2) + 4 * g;
            size_t p = (size_t)y * W + x0 + pxl;
            float pv0 = bf2f(pos_t[p * 64 + ln31]);
            float pv1 = bf2f(pos_t[p * 64 + 32 + ln31]);
            __hip_bfloat16* hp = &h[((size_t)lb * HW + p) * CO];
            hp[ln31]      = __float2bfloat16(c0[reg] + pv0 + b1v0);
            hp[32 + ln31] = __float2bfloat16(c1[reg] + pv1 + b1v1);
        }

        __syncthreads();
        if (s < 6) build(ys + 7, 4);   // rows for next window
        __syncthreads();
    }
}

// ---------------- kD: gather-reduce per (image, rank) -> pooled mean ----------------
__global__ void k_gather(const __hip_bfloat16* __restrict__ h,
                         const unsigned* __restrict__ bucket,
                         const int* __restrict__ off_rank,
                         const int* __restrict__ cnt_rank,
                         float* __restrict__ pooled, int b0) {
    const int tid = threadIdx.x;
    const int wave = tid >> 6, lane = tid & 63;
    const int r = blockIdx.x * 4 + wave;
    const int lb = blockIdx.y, b = b0 + lb;
    const int n = cnt_rank[b * SEG + r];
    const int base = off_rank[b * SEG + r];
    const int ps = lane >> 3, cg = lane & 7;

    float acc[8] = {0.f, 0.f, 0.f, 0.f, 0.f, 0.f, 0.f, 0.f};
    const unsigned* bk = &bucket[b * HW + base];
    const int iters = (n + 7) >> 3;
    for (int i = 0; i < iters; ++i) {
        int idx = i * 8 + ps;
        if (idx < n) {
            unsigned p = bk[idx];
            uint4 u = *(const uint4*)&h[((size_t)lb * HW + p) * CO + cg * 8];
            acc[0] += __uint_as_float((u.x & 0xffffu) << 16);
            acc[1] += __uint_as_float(u.x & 0xffff0000u);
            acc[2] += __uint_as_float((u.y & 0xffffu) << 16);
            acc[3] += __uint_as_float(u.y & 0xffff0000u);
            acc[4] += __uint_as_float((u.z & 0xffffu) << 16);
            acc[5] += __uint_as_float(u.z & 0xffff0000u);
            acc[6] += __uint_as_float((u.w & 0xffffu) << 16);
            acc[7] += __uint_as_float(u.w & 0xffff0000u);
        }
    }
    #pragma unroll
    for (int m = 8; m < 64; m <<= 1)
        #pragma unroll
        for (int j = 0; j < 8; ++j) acc[j] += __shfl_xor(acc[j], m, 64);

    if (ps == 0) {
        float inv = (n > 0) ? 1.f / (float)n : 0.f;
        float* op = &pooled[((size_t)b * SEG + r) * CO + cg * 8];
        float4 v0 = {acc[0] * inv, acc[1] * inv, acc[2] * inv, acc[3] * inv};
        float4 v1 = {acc[4] * inv, acc[5] * inv, acc[6] * inv, acc[7] * inv};
        *(float4*)&op[0] = v0;
        *(float4*)&op[4] = v1;
    }
}

// ---------------- kE: conv1d k=3 over pooled -> out ----------------
__launch_bounds__(256, 2)
__global__ void k_pool_conv1d(const float* __restrict__ pooledg,
                              const float* __restrict__ w2,
                              const float* __restrict__ b2,
                              float* __restrict__ out0) {
    __shared__ float pooled[CO * PP];
    __shared__ float w2l[192 * (EC + 1)];
    const int tid = threadIdx.x;
    const int b  = blockIdx.y;
    const int e0 = blockIdx.x * EC;

    for (int i = tid; i < SEG * CO; i += 256) {
        int s = i >> 6, c = i & 63;
        pooled[c * PP + s + 1] = pooledg[((size_t)b * SEG + s) * CO + c];
    }
    for (int i = tid; i < CO * 5; i += 256) {
        int c = i / 5, hh = i % 5;
        pooled[c * PP + (hh == 0 ? 0 : 196 + hh)] = 0.f;
    }
    for (int i = tid; i < EC * 192; i += 256) {
        int e = i / 192, k = i % 192;
        w2l[k * (EC + 1) + e] = w2[(size_t)(e0 + e) * 192 + k];
    }
    __syncthreads();

    const int txs = tid & 31;
    const int te  = tid >> 5;
    const int s0  = txs * 7;
    float acc[7][4];
    #pragma unroll
    for (int ss = 0; ss < 7; ++ss)
        #pragma unroll
        for (int ee = 0; ee < 4; ++ee) acc[ss][ee] = b2[e0 + te * 4 + ee];

    if (s0 < SEG) {
        #pragma unroll 4
        for (int c = 0; c < CO; ++c) {
            float pv[9];
            #pragma unroll
            for (int j = 0; j < 9; ++j) pv[j] = pooled[c * PP + s0 + j];
            #pragma unroll
            for (int dk = 0; dk < 3; ++dk) {
                float wv[4];
                #pragma unroll
                for (int ee = 0; ee < 4; ++ee)
                    wv[ee] = w2l[(c * 3 + dk) * (EC + 1) + te * 4 + ee];
                #pragma unroll
                for (int ss = 0; ss < 7; ++ss)
                    #pragma unroll
                    for (int ee = 0; ee < 4; ++ee)
                        acc[ss][ee] = fmaf(pv[ss + dk], wv[ee], acc[ss][ee]);
            }
        }
        #pragma unroll
        for (int ss = 0; ss < 7; ++ss) {
            int s = s0 + ss;
            float* op = &out0[((size_t)(b * SEG + s) * E) + e0 + te * 4];
            float4 v0 = {acc[ss][0], acc[ss][1], acc[ss][2], acc[ss][3]};
            *(float4*)op = v0;
        }
    }
}

extern "C" void kernel_launch(void* const* d_in, const int* in_sizes, int n_in,
                              void* d_out, int out_size, void* d_ws, size_t ws_size,
                              hipStream_t stream) {
    const float* x   = (const float*)d_in[0];
    const int*   seg = (const int*)d_in[1];
    const float* w1  = (const float*)d_in[2];
    const float* b1  = (const float*)d_in[3];
    const float* pos = (const float*)d_in[4];
    const float* w2  = (const float*)d_in[5];
    const float* b2  = (const float*)d_in[6];

    float* out0 = (float*)d_out;                 // [B,196,768]
    float* out2 = out0 + (size_t)B * SEG * E;    // f_segment as float [B,1,224,224]

    int*      present    = (int*)d_ws;                        // B*SEG [zeroed]
    unsigned* counts_raw = (unsigned*)(present + B * SEG);    // B*SEG [zeroed]
    int*      rank       = (int*)(counts_raw + B * SEG);
    int*      off_rank   = rank + B * SEG;
    int*      cnt_rank   = off_rank + B * SEG;
    unsigned* cursor     = (unsigned*)(cnt_rank + B * SEG);
    float*    pooled     = (float*)(cursor + B * SEG);                  // B*SEG*CO
    unsigned* bucket     = (unsigned*)(pooled + (size_t)B * SEG * CO);  // B*HW
    unsigned short* pos_t = (unsigned short*)(bucket + (size_t)B * HW); // HW*64 bf16
    __hip_bfloat16* hbuf = (__hip_bfloat16*)(pos_t + (size_t)HW * CO);

    hipMemsetAsync(d_ws, 0, (size_t)2 * B * SEG * 4, stream);

    k_post   <<<dim3(HW / 256), 256, 0, stream>>>(pos, pos_t);
    k_count  <<<dim3(28, B), 256, 0, stream>>>(seg, present, counts_raw);
    k_offsets<<<dim3(B),     256, 0, stream>>>(present, counts_raw, rank, off_rank, cnt_rank, cursor);
    k_scatter<<<dim3(28, B), 256, 0, stream>>>(seg, rank, cursor, bucket, out2);

    size_t used = (char*)hbuf - (char*)d_ws;
    size_t h_per_img = (size_t)HW * CO * sizeof(__hip_bfloat16);  // 6.42 MB
    size_t avail = (ws_size > used) ? ws_size - used : 0;
    int ipc = (int)(avail / h_per_img);
    if (ipc < 1) ipc = 1;
    if (ipc > B) ipc = B;

    for (int b0 = 0; b0 < B; b0 += ipc) {
        int nb = (b0 + ipc <= B) ? ipc : (B - b0);
        k_conv_mfma<<<dim3(nb, 7, 8), 256, 0, stream>>>(x, w1, b1, pos_t, hbuf, b0);
        k_gather   <<<dim3(49, nb),   256, 0, stream>>>(hbuf, bucket, off_rank, cnt_rank, pooled, b0);
    }
    k_pool_conv1d<<<dim3(24, B), 256, 0, stream>>>(pooled, w2, b2, out0);
}